// Round 17
// baseline (500.827 us; speedup 1.0000x reference)
//
#include <hip/hip_runtime.h>
#include <hip/hip_bf16.h>

#define FLT_BIG 3.0e38f

typedef __attribute__((ext_vector_type(8))) short s8v;
typedef __attribute__((ext_vector_type(4))) float f4v;

// ---------------------------------------------------------------------------
// bf16 2-plane split, RNE. x ~= x0 + x1 with residual <= 2^-18 |x|.
// ---------------------------------------------------------------------------
__device__ inline void split2(float v, unsigned short& h0, unsigned short& h1) {
    unsigned int u = __float_as_uint(v);
    unsigned int r0 = (u + 0x7FFFu + ((u >> 16) & 1u)) >> 16;
    h0 = (unsigned short)r0;
    float r = v - __uint_as_float(r0 << 16);
    unsigned int u2 = __float_as_uint(r);
    h1 = (unsigned short)((u2 + 0x7FFFu + ((u2 >> 16) & 1u)) >> 16);
}

// MFMA plane-combo steps (2-plane): (1,0), (0,1), (0,0) — smallest first.
#define SA2_P1(AI, BI)                                                          \
    _Pragma("unroll") for (int oi = 0; oi < 2; oi++) {                          \
        _Pragma("unroll") for (int jf = 0; jf < 4; jf++)                        \
            acc1[oi][jf] = __builtin_amdgcn_mfma_f32_16x16x32_bf16(             \
                aw[oi][AI], bfr[jf][BI], acc1[oi][jf], 0, 0, 0);                \
    }
#define SA1_P1(AI, BI)                                                          \
    _Pragma("unroll") for (int jf = 0; jf < 4; jf++)                            \
        acc1[jf] = __builtin_amdgcn_mfma_f32_16x16x32_bf16(                     \
            aw[AI], bfr[jf][BI], acc1[jf], 0, 0, 0);
#define MM_P2(AI, BI)                                                           \
    _Pragma("unroll") for (int oi = 0; oi < 2; oi++) {                          \
        _Pragma("unroll") for (int jf = 0; jf < 4; jf++)                        \
            acc2[oi][jf] = __builtin_amdgcn_mfma_f32_16x16x32_bf16(             \
                af[jf][AI], gw[oi][BI], acc2[oi][jf], 0, 0, 0);                 \
    }
#define SA3_P(AI, BI)                                                           \
    _Pragma("unroll") for (int oi = 0; oi < 2; oi++) {                          \
        _Pragma("unroll") for (int j = 0; j < 4; j++)                           \
            acc[oi][ph * 4 + j] = __builtin_amdgcn_mfma_f32_16x16x32_bf16(      \
                aw[oi][AI], bfh[j][BI], acc[oi][ph * 4 + j], 0, 0, 0);          \
    }

// Monotonic key for d2, pinned FMA order (identical everywhere).
#define MKKEY(QX, QY, QZ, XS)                                                   \
    ({  float dot_ = fmaf((QZ), yz, fmaf((QY), yy, (QX) * yx));                 \
        float d2_ = fmaf(-2.0f, dot_, (XS) + ys);                               \
        unsigned int kk_ = __float_as_uint(d2_);                                \
        (kk_ & 0x80000000u) ? ~kk_ : (kk_ | 0x80000000u); })

// ---------------------------------------------------------------------------
// Multi-job weight fragment precompute (2 planes).
// ---------------------------------------------------------------------------
struct WfragJob { const float* W; int K, stride, off, no; unsigned short* out; };
struct WfragJobs { WfragJob j[4]; int start[5]; };

__global__ __launch_bounds__(64) void wfrag_multi(WfragJobs jobs) {
    int bid = blockIdx.x;
    int ji = 3;
    if (bid < jobs.start[1]) ji = 0;
    else if (bid < jobs.start[2]) ji = 1;
    else if (bid < jobs.start[3]) ji = 2;
    const WfragJob& J = jobs.j[ji];
    int lb = bid - jobs.start[ji];
    int l = threadIdx.x;
    int ks = lb / J.no, ot = lb - ks * J.no;
    int o = ot * 16 + (l & 15);
    int k0 = ks * 32 + (l >> 4) * 8;
    const float* src = J.W + (size_t)o * J.stride + J.off + k0;
    unsigned short h[2][8];
#pragma unroll
    for (int e = 0; e < 8; e++) split2(src[e], h[0][e], h[1][e]);
#pragma unroll
    for (int p = 0; p < 2; p++) {
        s8v v;
#pragma unroll
        for (int e = 0; e < 8; e++) v[e] = (short)h[p][e];
        *(s8v*)(J.out + ((size_t)(lb * 2 + p) * 64 + l) * 8) = v;
    }
}

// ---------------------------------------------------------------------------
// kNN v4: 4 queries/block (round-15 structure) + REGISTER key-cache.
// Each thread owns points n = t + i*256 (i < NITER = N_pts/256); top-16 key
// bits for all 4 queries live in kc01/kc23 (statically indexed, full unroll).
// Pass C: 2 ALU per point-query; full key recomputed only for boundary cands.
// Selection exact: same MKKEY, (key, idx) lexicographic rank.
// ---------------------------------------------------------------------------
#define KNN_CAP 192
template<int NITER>
__global__ __launch_bounds__(256) void knn4r_kernel(
    const float* __restrict__ x, int K, int P,
    int* __restrict__ idx_out, unsigned short* __restrict__ idx16) {
    const int N_pts = NITER * 256;
    int bq = blockIdx.x;
    int pg = P >> 2;
    int b = bq / pg, p0 = (bq - b * pg) * 4;
    const float* xyz = x + (size_t)b * 24576;
    __shared__ unsigned int hist[2][2048];   // packed u16 pairs: q0/q1, q2/q3
    __shared__ unsigned int candK[4][KNN_CAP];
    __shared__ int candI[4][KNN_CAP];
    __shared__ int outIdx[4][64];
    __shared__ unsigned int cnts[4][2];
    __shared__ int sB[4], sM[4];
    __shared__ float qcoord[4][4];
    int t = threadIdx.x;
    int w = t >> 6, lane = t & 63;
    for (int i = t; i < 4096; i += 256) ((unsigned int*)hist)[i] = 0u;
    if (t < 8) cnts[t >> 1][t & 1] = 0u;
    float qx[4], qy[4], qz[4], xs[4];
#pragma unroll
    for (int q = 0; q < 4; q++) {
        float a = xyz[p0 + q], c1 = xyz[4096 + p0 + q], c2 = xyz[8192 + p0 + q];
        qx[q] = a; qy[q] = c1; qz[q] = c2;
        xs[q] = fmaf(c2, c2, fmaf(c1, c1, a * a));
    }
    if (t < 4) {
        qcoord[t][0] = qx[t]; qcoord[t][1] = qy[t];
        qcoord[t][2] = qz[t]; qcoord[t][3] = xs[t];
    }
    __syncthreads();
    // ---- pass A: histogram + register k16 cache
    unsigned int kc01[NITER], kc23[NITER];
#pragma unroll
    for (int i = 0; i < NITER; i++) {
        int n = t + i * 256;
        float yx = xyz[n], yy = xyz[4096 + n], yz = xyz[8192 + n];
        float ys = fmaf(yz, yz, fmaf(yy, yy, yx * yx));
        unsigned int k0 = MKKEY(qx[0], qy[0], qz[0], xs[0]);
        unsigned int k1 = MKKEY(qx[1], qy[1], qz[1], xs[1]);
        unsigned int k2 = MKKEY(qx[2], qy[2], qz[2], xs[2]);
        unsigned int k3 = MKKEY(qx[3], qy[3], qz[3], xs[3]);
        atomicAdd(&hist[0][k0 >> 21], 1u);
        atomicAdd(&hist[0][k1 >> 21], 0x10000u);
        atomicAdd(&hist[1][k2 >> 21], 1u);
        atomicAdd(&hist[1][k3 >> 21], 0x10000u);
        kc01[i] = (k0 >> 16) | (k1 & 0xFFFF0000u);
        kc23[i] = (k2 >> 16) | (k3 & 0xFFFF0000u);
    }
    __syncthreads();
    // ---- pass B: wave w scans query w's histogram
    {
        int pair = w >> 1, sh = (w & 1) * 16;
        unsigned int lsum = 0;
        for (int i = 0; i < 32; i++)
            lsum += (hist[pair][lane * 32 + i] >> sh) & 0xFFFFu;
        unsigned int incl = lsum;
        for (int ss = 1; ss < 64; ss <<= 1) {
            unsigned int v = (unsigned int)__shfl_up((int)incl, ss);
            if (lane >= ss) incl += v;
        }
        unsigned int excl = incl - lsum;
        if (excl < (unsigned)K && excl + lsum >= (unsigned)K) {
            unsigned int cum = excl;
            for (int i = 0; i < 32; i++) {
                unsigned int h = (hist[pair][lane * 32 + i] >> sh) & 0xFFFFu;
                if (cum < (unsigned)K && cum + h >= (unsigned)K) {
                    sB[w] = lane * 32 + i; sM[w] = (int)cum; break;
                }
                cum += h;
            }
        }
    }
    __syncthreads();
    // ---- pass C: classify from register cache (bin = k16 >> 5 exactly)
#pragma unroll
    for (int i = 0; i < NITER; i++) {
        int n = t + i * 256;
        unsigned int c01 = kc01[i], c23 = kc23[i];
#pragma unroll
        for (int q = 0; q < 4; q++) {
            unsigned int k16 = (q == 0) ? (c01 & 0xFFFFu) :
                               (q == 1) ? (c01 >> 16) :
                               (q == 2) ? (c23 & 0xFFFFu) : (c23 >> 16);
            int bin = (int)(k16 >> 5);
            int Bq = sB[q];
            if (bin < Bq) {
                outIdx[q][atomicAdd(&cnts[q][0], 1u)] = n;
            } else if (bin == Bq) {
                unsigned int ci = atomicAdd(&cnts[q][1], 1u);
                if (ci < KNN_CAP) {
                    float yx = xyz[n], yy = xyz[4096 + n], yz = xyz[8192 + n];
                    float ys = fmaf(yz, yz, fmaf(yy, yy, yx * yx));
                    unsigned int key = MKKEY(qx[q], qy[q], qz[q], xs[q]);
                    candK[q][ci] = key; candI[q][ci] = n;
                }
            }
        }
    }
    __syncthreads();
    // ---- pass D: per-wave rank-select for query w
    {
        int nc = (int)cnts[w][1];
        int m = sM[w], r = K - m, Bw = sB[w];
        if (nc <= KNN_CAP) {
            for (int ci = lane; ci < nc; ci += 64) {
                unsigned int ki = candK[w][ci];
                int ii = candI[w][ci];
                int rank = 0;
                for (int j = 0; j < nc; j++) {
                    unsigned int kj = candK[w][j];
                    rank += (kj < ki || (kj == ki && candI[w][j] < ii)) ? 1 : 0;
                }
                if (rank < r) outIdx[w][m + rank] = ii;
            }
        } else {
            // fallback (never hit for benign data): successive wave-argmin
            float fqx = qcoord[w][0], fqy = qcoord[w][1];
            float fqz = qcoord[w][2], fxs = qcoord[w][3];
            unsigned int lastK = 0u; int lastI = -1;
            for (int rr = 0; rr < r; rr++) {
                unsigned int bk = 0xFFFFFFFFu; int bi = 0x7fffffff;
                for (int n = lane; n < N_pts; n += 64) {
                    float yx = xyz[n], yy = xyz[4096 + n], yz = xyz[8192 + n];
                    float ys = fmaf(yz, yz, fmaf(yy, yy, yx * yx));
                    unsigned int key = MKKEY(fqx, fqy, fqz, fxs);
                    if ((int)(key >> 21) == Bw) {
                        bool gt = (key > lastK) || (key == lastK && n > lastI);
                        if (gt && (key < bk || (key == bk && n < bi))) { bk = key; bi = n; }
                    }
                }
#pragma unroll
                for (int ss = 32; ss > 0; ss >>= 1) {
                    unsigned int ok = (unsigned int)__shfl_xor((int)bk, ss);
                    int oi = __shfl_xor(bi, ss);
                    if (ok < bk || (ok == bk && oi < bi)) { bk = ok; bi = oi; }
                }
                if (lane == 0) outIdx[w][m + rr] = bi;
                lastK = bk; lastI = bi;
            }
        }
    }
    __syncthreads();
    if (t < 4 * K) {
        int q = t / K, k = t - q * K;
        size_t off = ((size_t)(b * P) + p0 + q) * K + k;
        if (idx16) idx16[off] = (unsigned short)outIdx[q][k];
        else idx_out[off] = outIdx[q][k];
    }
}

// ---------------------------------------------------------------------------
// SA1 precompute: A1t[b][n][o] = b1[o] + sum_c w1[o][c]*x[b][c][n].
// ---------------------------------------------------------------------------
__global__ __launch_bounds__(256) void sa1_pre_kernel(
    const float* __restrict__ x, const float* __restrict__ w1, const float* __restrict__ b1,
    float* __restrict__ a1t) {
    int bid = blockIdx.x;
    int b = bid >> 5, nt = bid & 31, n0 = nt << 7;
    __shared__ float xsh[6 * 128];
    __shared__ float wt[6 * 68];
    const float* xb = x + (size_t)b * 24576;
    int t = threadIdx.x;
    for (int id = t; id < 768; id += 256) {
        int c = id >> 7, n = id & 127;
        xsh[c * 128 + n] = xb[c * 4096 + n0 + n];
    }
    for (int id = t; id < 384; id += 256) {
        int c = id >> 6, o = id & 63;
        wt[c * 68 + o] = w1[o * 6 + c];
    }
    __syncthreads();
    int o = t & 63, ng = t >> 6;
    float acc[32];
    float bias = b1[o];
#pragma unroll
    for (int j = 0; j < 32; j++) acc[j] = bias;
    for (int c = 0; c < 6; c++) {
        float w = wt[c * 68 + o];
        const float* f = &xsh[c * 128 + ng * 32];
#pragma unroll
        for (int j = 0; j < 32; j++) acc[j] += w * f[j];
    }
#pragma unroll
    for (int j = 0; j < 32; j++)
        a1t[((size_t)b * 4096 + n0 + ng * 32 + j) * 64 + o] = acc[j];
}

// ---------------------------------------------------------------------------
// SA1 MFMA fused (2-plane).
// ---------------------------------------------------------------------------
__global__ __launch_bounds__(256) void sa1_mfma_kernel(
    const float* __restrict__ x, const float* __restrict__ a1t,
    const int* __restrict__ idx1, const float* __restrict__ w1,
    const unsigned short* __restrict__ w2f, const float* __restrict__ b2,
    const unsigned short* __restrict__ w3f, const float* __restrict__ b3,
    float* __restrict__ p1) {
    int bp = blockIdx.x;  // 32*256
    int b = bp >> 8, pp = bp & 255, p0 = pp * 2;
    __shared__ float dshq[2][64];
    __shared__ int nbr[64];
    __shared__ unsigned short A1buf[8 * 2 * 64 * 8];  // 16KB
    __shared__ float MX[2][128];
    const float* xb = x + (size_t)b * 24576;
    int t = threadIdx.x;
    int w = t >> 6, l = t & 63;
    int n16 = l & 15, og = l >> 4;
    if (t < 64) nbr[t] = idx1[((size_t)b * 512 + p0) * 32 + t];
    if (t < 128) {
        int qi = t >> 6, c = t & 63;
        float qx = xb[p0 + qi], qy = xb[4096 + p0 + qi], qz = xb[8192 + p0 + qi];
        dshq[qi][c] = -(w1[c * 6 + 0] * qx + w1[c * 6 + 1] * qy + w1[c * 6 + 2] * qz);
    }
    __syncthreads();
    int q = w >> 1;
    f4v acc1[4];
#pragma unroll
    for (int jf = 0; jf < 4; jf++) acc1[jf] = (f4v){0.f, 0.f, 0.f, 0.f};
    const float* gsrc = a1t + ((size_t)b * 4096 + nbr[w * 16 + n16]) * 64 + og * 8;
    f4v nv0 = *(const f4v*)(gsrc);
    f4v nv1 = *(const f4v*)(gsrc + 4);
    s8v nw[2];
    {
        const s8v* wr = (const s8v*)w2f;
#pragma unroll
        for (int pl = 0; pl < 2; pl++) nw[pl] = wr[(w * 2 + pl) * 64 + l];
    }
    for (int ks = 0; ks < 2; ks++) {
        f4v v0 = nv0, v1 = nv1;
        s8v aw[2];
#pragma unroll
        for (int pl = 0; pl < 2; pl++) aw[pl] = nw[pl];
        if (ks < 1) {
            nv0 = *(const f4v*)(gsrc + 32);
            nv1 = *(const f4v*)(gsrc + 36);
            const s8v* wr = (const s8v*)w2f + (size_t)4 * 2 * 64;
#pragma unroll
            for (int pl = 0; pl < 2; pl++) nw[pl] = wr[(w * 2 + pl) * 64 + l];
        }
        unsigned short* BFD = A1buf + (ks & 1) * 4096;
        const float* d = &dshq[q][ks * 32 + og * 8];
        s8v sp0, sp1;
#pragma unroll
        for (int e = 0; e < 8; e++) {
            float hv = fmaxf(((e < 4) ? v0[e] : v1[e - 4]) + d[e], 0.f);
            unsigned short h0, h1;
            split2(hv, h0, h1);
            sp0[e] = (short)h0; sp1[e] = (short)h1;
        }
        *(s8v*)&BFD[((w * 2 + 0) * 64 + l) * 8] = sp0;
        *(s8v*)&BFD[((w * 2 + 1) * 64 + l) * 8] = sp1;
        __syncthreads();
        s8v bfr[4][2];
#pragma unroll
        for (int jf = 0; jf < 4; jf++)
#pragma unroll
            for (int pl = 0; pl < 2; pl++)
                bfr[jf][pl] = *(const s8v*)&BFD[((jf * 2 + pl) * 64 + l) * 8];
        SA1_P1(1, 0) SA1_P1(0, 1) SA1_P1(0, 0)
    }
    __syncthreads();  // all waves done reading BF before handoff overwrites
    {
        f4v bv = *(const f4v*)(b2 + w * 16 + og * 4);
        int l2 = n16 + ((w & 1) * 2 + (og >> 1)) * 16;
        int half = og & 1;
#pragma unroll
        for (int jf = 0; jf < 4; jf++) {
            unsigned short hh[2][4];
#pragma unroll
            for (int r = 0; r < 4; r++) {
                float y = fmaxf(acc1[jf][r] + bv[r], 0.f);
                split2(y, hh[0][r], hh[1][r]);
            }
            int slot = (w >> 1) * 4 + jf;
#pragma unroll
            for (int pl = 0; pl < 2; pl++) {
                unsigned long long pk = (unsigned long long)hh[pl][0] |
                    ((unsigned long long)hh[pl][1] << 16) |
                    ((unsigned long long)hh[pl][2] << 32) |
                    ((unsigned long long)hh[pl][3] << 48);
                *(unsigned long long*)&A1buf[((slot * 2 + pl) * 64 + l2) * 8 + half * 4] = pk;
            }
        }
    }
    __syncthreads();
    f4v acc2[2][4];
#pragma unroll
    for (int oi = 0; oi < 2; oi++)
#pragma unroll
        for (int jf = 0; jf < 4; jf++) acc2[oi][jf] = (f4v){0.f, 0.f, 0.f, 0.f};
    for (int ks2 = 0; ks2 < 2; ks2++) {
        s8v af[4][2];
#pragma unroll
        for (int jf = 0; jf < 4; jf++)
#pragma unroll
            for (int pl = 0; pl < 2; pl++)
                af[jf][pl] = *(const s8v*)&A1buf[(((ks2 * 4 + jf) * 2 + pl) * 64 + l) * 8];
        const s8v* wr = (const s8v*)w3f + (size_t)(ks2 * 8) * 2 * 64;
        s8v gw[2][2];
#pragma unroll
        for (int oi = 0; oi < 2; oi++)
#pragma unroll
            for (int pl = 0; pl < 2; pl++)
                gw[oi][pl] = wr[((w * 2 + oi) * 2 + pl) * 64 + l];
        MM_P2(1, 0) MM_P2(0, 1) MM_P2(0, 0)
    }
#pragma unroll
    for (int oi = 0; oi < 2; oi++) {
        float m0 = fmaxf(fmaxf(acc2[oi][0][0], acc2[oi][0][1]),
                         fmaxf(acc2[oi][0][2], acc2[oi][0][3]));
        m0 = fmaxf(m0, fmaxf(fmaxf(acc2[oi][1][0], acc2[oi][1][1]),
                             fmaxf(acc2[oi][1][2], acc2[oi][1][3])));
        float m1 = fmaxf(fmaxf(acc2[oi][2][0], acc2[oi][2][1]),
                         fmaxf(acc2[oi][2][2], acc2[oi][2][3]));
        m1 = fmaxf(m1, fmaxf(fmaxf(acc2[oi][3][0], acc2[oi][3][1]),
                             fmaxf(acc2[oi][3][2], acc2[oi][3][3])));
        m0 = fmaxf(m0, __shfl_xor(m0, 16));
        m0 = fmaxf(m0, __shfl_xor(m0, 32));
        m1 = fmaxf(m1, __shfl_xor(m1, 16));
        m1 = fmaxf(m1, __shfl_xor(m1, 32));
        if (og == 0) {
            MX[0][(w * 2 + oi) * 16 + n16] = m0;
            MX[1][(w * 2 + oi) * 16 + n16] = m1;
        }
    }
    __syncthreads();
    {
        int o = t & 127, qq = t >> 7;
        p1[((size_t)b * 128 + o) * 512 + p0 + qq] = MX[qq][o] + b3[o];
    }
}

// ---------------------------------------------------------------------------
// SA2 precompute (unchanged, fp32 exact).
// ---------------------------------------------------------------------------
__global__ __launch_bounds__(256) void sa2_pre_kernel(
    const float* __restrict__ x, const float* __restrict__ p1,
    const float* __restrict__ w1, const float* __restrict__ b1,
    float* __restrict__ a2t) {
    int bid = blockIdx.x;
    int b = bid >> 2, nt = bid & 3, n0 = nt << 7;
    __shared__ float ins[2][16 * 128];
    __shared__ float wt[2][16 * 132];
    const float* xb = x + (size_t)b * 24576;
    const float* p1b = p1 + (size_t)b * 65536;
    int t = threadIdx.x;
    int og = t >> 3, pg = t & 7;
    int o0 = og * 4;
    float acc[4][16];
    {
        float bl[4] = {b1[o0], b1[o0 + 1], b1[o0 + 2], b1[o0 + 3]};
#pragma unroll
        for (int oi = 0; oi < 4; oi++)
#pragma unroll
            for (int j = 0; j < 16; j++) acc[oi][j] = bl[oi];
    }
    for (int id = t; id < 16 * 128; id += 256) {
        int n = id & 127, c = id >> 7;
        ins[0][c * 128 + n] = (c < 3) ? xb[c * 4096 + n0 + n]
                                      : p1b[(size_t)(c - 3) * 512 + n0 + n];
    }
    for (int id = t; id < 2048; id += 256) {
        int c = id & 15, oo = id >> 4;
        wt[0][c * 132 + oo] = w1[oo * 131 + c];
    }
    __syncthreads();
    for (int ch = 0; ch < 9; ch++) {
        int cs = (ch == 8) ? 3 : 16;
        if (ch < 8) {
            int c0n = (ch + 1) * 16;
            int csn = (ch == 7) ? 3 : 16;
            int nb = (ch + 1) & 1;
            for (int id = t; id < csn * 128; id += 256) {
                int n = id & 127, c = id >> 7;
                int cg = c0n + c;
                ins[nb][c * 128 + n] = (cg < 3) ? xb[cg * 4096 + n0 + n]
                                                : p1b[(size_t)(cg - 3) * 512 + n0 + n];
            }
            for (int id = t; id < 2048; id += 256) {
                int c = id & 15, oo = id >> 4;
                if (c < csn) wt[nb][c * 132 + oo] = w1[oo * 131 + c0n + c];
            }
        }
        const float* wb = wt[ch & 1];
        const float* ib = ins[ch & 1];
        for (int cc = 0; cc < cs; cc++) {
            float4 wv = *(const float4*)&wb[cc * 132 + o0];
            float wl[4] = {wv.x, wv.y, wv.z, wv.w};
#pragma unroll
            for (int c4 = 0; c4 < 4; c4++) {
                float4 fv = *(const float4*)&ib[cc * 128 + pg * 4 + c4 * 32];
                float fl[4] = {fv.x, fv.y, fv.z, fv.w};
#pragma unroll
                for (int j = 0; j < 4; j++)
#pragma unroll
                    for (int oi = 0; oi < 4; oi++) acc[oi][c4 * 4 + j] += wl[oi] * fl[j];
            }
        }
        __syncthreads();
    }
#pragma unroll
    for (int c4 = 0; c4 < 4; c4++)
#pragma unroll
        for (int j = 0; j < 4; j++) {
            int n = n0 + pg * 4 + c4 * 32 + j;
            float4 v;
            v.x = acc[0][c4 * 4 + j]; v.y = acc[1][c4 * 4 + j];
            v.z = acc[2][c4 * 4 + j]; v.w = acc[3][c4 * 4 + j];
            *(float4*)&a2t[((size_t)b * 512 + n) * 128 + o0] = v;
        }
}

// ---------------------------------------------------------------------------
// SA2 MFMA fused (2-plane). idx2 is u16.
// ---------------------------------------------------------------------------
__global__ __launch_bounds__(256) void sa2_mfma_kernel(
    const float* __restrict__ x, const float* __restrict__ a2t,
    const unsigned short* __restrict__ idx2, const float* __restrict__ w1,
    const unsigned short* __restrict__ w2f, const float* __restrict__ b2,
    const unsigned short* __restrict__ w3f, const float* __restrict__ b3,
    unsigned short* __restrict__ p2f) {
    int bp = blockIdx.x;  // 32*128
    int b = bp >> 7, p = bp & 127;
    __shared__ float dsh[128];
    __shared__ int nbr[64];
    __shared__ unsigned short A2buf[16 * 2 * 64 * 8];  // 32KB
    __shared__ float MX[256];
    const float* xb = x + (size_t)b * 24576;
    int t = threadIdx.x;
    int w = t >> 6, l = t & 63;
    int n16 = l & 15, og = l >> 4;
    if (t < 64) nbr[t] = (int)idx2[((size_t)b * 128 + p) * 64 + t];
    if (t < 128) {
        float qx = xb[p], qy = xb[4096 + p], qz = xb[8192 + p];
        dsh[t] = -(w1[t * 131 + 0] * qx + w1[t * 131 + 1] * qy + w1[t * 131 + 2] * qz);
    }
    __syncthreads();
    f4v acc1[2][4];
#pragma unroll
    for (int oi = 0; oi < 2; oi++)
#pragma unroll
        for (int jf = 0; jf < 4; jf++) acc1[oi][jf] = (f4v){0.f, 0.f, 0.f, 0.f};
    const float* gsrc = a2t + ((size_t)b * 512 + nbr[w * 16 + n16]) * 128 + og * 8;
    f4v nv0 = *(const f4v*)(gsrc);
    f4v nv1 = *(const f4v*)(gsrc + 4);
    s8v nw[2][2];
    {
        const s8v* wr = (const s8v*)w2f;
#pragma unroll
        for (int oi = 0; oi < 2; oi++)
#pragma unroll
            for (int pl = 0; pl < 2; pl++)
                nw[oi][pl] = wr[((w * 2 + oi) * 2 + pl) * 64 + l];
    }
    for (int ks = 0; ks < 4; ks++) {
        f4v v0 = nv0, v1 = nv1;
        s8v aw[2][2];
#pragma unroll
        for (int oi = 0; oi < 2; oi++)
#pragma unroll
            for (int pl = 0; pl < 2; pl++) aw[oi][pl] = nw[oi][pl];
        if (ks < 3) {
            nv0 = *(const f4v*)(gsrc + (ks + 1) * 32);
            nv1 = *(const f4v*)(gsrc + (ks + 1) * 32 + 4);
            const s8v* wr = (const s8v*)w2f + (size_t)((ks + 1) * 8) * 2 * 64;
#pragma unroll
            for (int oi = 0; oi < 2; oi++)
#pragma unroll
                for (int pl = 0; pl < 2; pl++)
                    nw[oi][pl] = wr[((w * 2 + oi) * 2 + pl) * 64 + l];
        }
        unsigned short* BFD = A2buf + (ks & 1) * 4096;
        const float* d = &dsh[ks * 32 + og * 8];
        s8v sp0, sp1;
#pragma unroll
        for (int e = 0; e < 8; e++) {
            float hv = fmaxf(((e < 4) ? v0[e] : v1[e - 4]) + d[e], 0.f);
            unsigned short h0, h1;
            split2(hv, h0, h1);
            sp0[e] = (short)h0; sp1[e] = (short)h1;
        }
        *(s8v*)&BFD[((w * 2 + 0) * 64 + l) * 8] = sp0;
        *(s8v*)&BFD[((w * 2 + 1) * 64 + l) * 8] = sp1;
        __syncthreads();
        s8v bfr[4][2];
#pragma unroll
        for (int jf = 0; jf < 4; jf++)
#pragma unroll
            for (int pl = 0; pl < 2; pl++)
                bfr[jf][pl] = *(const s8v*)&BFD[((jf * 2 + pl) * 64 + l) * 8];
        SA2_P1(1, 0) SA2_P1(0, 1) SA2_P1(0, 0)
    }
    __syncthreads();  // all waves done reading BF before handoff overwrites
#pragma unroll
    for (int oi = 0; oi < 2; oi++) {
        int ot = w * 2 + oi;
        f4v bv = *(const f4v*)(b2 + ot * 16 + og * 4);
        int l2 = n16 + (oi * 2 + (og >> 1)) * 16;
        int half = og & 1;
#pragma unroll
        for (int jf = 0; jf < 4; jf++) {
            unsigned short hh[2][4];
#pragma unroll
            for (int r = 0; r < 4; r++) {
                float y = fmaxf(acc1[oi][jf][r] + bv[r], 0.f);
                split2(y, hh[0][r], hh[1][r]);
            }
            int slot = w * 4 + jf;
#pragma unroll
            for (int pl = 0; pl < 2; pl++) {
                unsigned long long pk = (unsigned long long)hh[pl][0] |
                    ((unsigned long long)hh[pl][1] << 16) |
                    ((unsigned long long)hh[pl][2] << 32) |
                    ((unsigned long long)hh[pl][3] << 48);
                *(unsigned long long*)&A2buf[((slot * 2 + pl) * 64 + l2) * 8 + half * 4] = pk;
            }
        }
    }
    __syncthreads();
#pragma unroll
    for (int half2 = 0; half2 < 2; half2++) {
        f4v acc2[2][4];
#pragma unroll
        for (int oi = 0; oi < 2; oi++)
#pragma unroll
            for (int jf = 0; jf < 4; jf++) acc2[oi][jf] = (f4v){0.f, 0.f, 0.f, 0.f};
        for (int ks2 = 0; ks2 < 4; ks2++) {
            s8v af[4][2];
#pragma unroll
            for (int jf = 0; jf < 4; jf++)
#pragma unroll
                for (int pl = 0; pl < 2; pl++)
                    af[jf][pl] = *(const s8v*)&A2buf[(((ks2 * 4 + jf) * 2 + pl) * 64 + l) * 8];
            const s8v* wr = (const s8v*)w3f + (size_t)(ks2 * 16) * 2 * 64;
            s8v gw[2][2];
#pragma unroll
            for (int oi = 0; oi < 2; oi++)
#pragma unroll
                for (int pl = 0; pl < 2; pl++)
                    gw[oi][pl] = wr[((w * 4 + half2 * 2 + oi) * 2 + pl) * 64 + l];
            MM_P2(1, 0) MM_P2(0, 1) MM_P2(0, 0)
        }
#pragma unroll
        for (int oi = 0; oi < 2; oi++) {
            float m = -FLT_BIG;
#pragma unroll
            for (int jf = 0; jf < 4; jf++) {
                float mj = fmaxf(fmaxf(acc2[oi][jf][0], acc2[oi][jf][1]),
                                 fmaxf(acc2[oi][jf][2], acc2[oi][jf][3]));
                m = fmaxf(m, mj);
            }
            m = fmaxf(m, __shfl_xor(m, 16));
            m = fmaxf(m, __shfl_xor(m, 32));
            if (og == 0) MX[(w * 4 + half2 * 2 + oi) * 16 + n16] = m;
        }
    }
    __syncthreads();
    {   // write p2 channel t for point p as SA3-layer1 B-frag planes (2-plane)
        float val = MX[t] + b3[t];
        unsigned short h0, h1;
        split2(val, h0, h1);
        int pt = p >> 4;
        int ks = t >> 5, kl = t & 31;
        int l2 = (p & 15) + (kl >> 3) * 16;
        int e = kl & 7;
        size_t fb = (((size_t)b * 64 + ks * 8 + pt) * 2) * 512 + l2 * 8 + e;
        p2f[fb] = h0;
        p2f[fb + 512] = h1;
    }
}

// ---------------------------------------------------------------------------
// SA3 GEMM over 128 points, MFMA, 2-plane frag I/O.
// ---------------------------------------------------------------------------
__global__ __launch_bounds__(64) void sa3_mfma_kernel(
    const unsigned short* __restrict__ hf_in, const unsigned short* __restrict__ wf,
    const float* __restrict__ bias, int nks, int noCout,
    unsigned short* __restrict__ hf_out, int nksOut,
    float* __restrict__ gout, int reduce) {
    int nb = noCout >> 1;
    int bid = blockIdx.x;
    int b = bid / nb, u = bid - b * nb;
    int ot0 = u * 2;
    int l = threadIdx.x;
    f4v acc[2][8];
#pragma unroll
    for (int oi = 0; oi < 2; oi++)
#pragma unroll
        for (int j = 0; j < 8; j++) acc[oi][j] = (f4v){0.f, 0.f, 0.f, 0.f};
    const unsigned short* hb = hf_in + (size_t)b * nks * 8 * 2 * 512;
    for (int ks = 0; ks < nks; ks++) {
        s8v aw[2][2];
#pragma unroll
        for (int oi = 0; oi < 2; oi++)
#pragma unroll
            for (int pl = 0; pl < 2; pl++)
                aw[oi][pl] = *(const s8v*)&wf[(((size_t)(ks * noCout + ot0 + oi)) * 2 + pl) * 512 + l * 8];
#pragma unroll
        for (int ph = 0; ph < 2; ph++) {
            s8v bfh[4][2];
#pragma unroll
            for (int j = 0; j < 4; j++)
#pragma unroll
                for (int pl = 0; pl < 2; pl++)
                    bfh[j][pl] = *(const s8v*)&hb[(((size_t)(ks * 8 + ph * 4 + j)) * 2 + pl) * 512 + l * 8];
            SA3_P(1, 0) SA3_P(0, 1) SA3_P(0, 0)
        }
    }
    if (!reduce) {
#pragma unroll
        for (int oi = 0; oi < 2; oi++) {
            int OT = ot0 + oi;
            f4v bv = *(const f4v*)(bias + OT * 16 + (l >> 4) * 4);
            int ksp = OT >> 1;
            int l2 = (l & 15) + ((OT & 1) * 2 + ((l >> 4) >> 1)) * 16;
            int base4 = ((l >> 4) & 1) * 4;
#pragma unroll
            for (int pt = 0; pt < 8; pt++) {
                unsigned short hh[2][4];
#pragma unroll
                for (int r = 0; r < 4; r++) {
                    float y = fmaxf(acc[oi][pt][r] + bv[r], 0.f);
                    split2(y, hh[0][r], hh[1][r]);
                }
#pragma unroll
                for (int pl = 0; pl < 2; pl++) {
                    unsigned long long pk = (unsigned long long)hh[pl][0] |
                        ((unsigned long long)hh[pl][1] << 16) |
                        ((unsigned long long)hh[pl][2] << 32) |
                        ((unsigned long long)hh[pl][3] << 48);
                    *(unsigned long long*)&hf_out[
                        (((size_t)b * nksOut * 8 + ksp * 8 + pt) * 2 + pl) * 512 + l2 * 8 + base4] = pk;
                }
            }
        }
    } else {
        int Cout = noCout * 16;
#pragma unroll
        for (int oi = 0; oi < 2; oi++) {
            int OT = ot0 + oi;
#pragma unroll
            for (int r = 0; r < 4; r++) {
                float m = acc[oi][0][r];
#pragma unroll
                for (int pt = 1; pt < 8; pt++) m = fmaxf(m, acc[oi][pt][r]);
                m = fmaxf(m, __shfl_xor(m, 1));
                m = fmaxf(m, __shfl_xor(m, 2));
                m = fmaxf(m, __shfl_xor(m, 4));
                m = fmaxf(m, __shfl_xor(m, 8));
                if ((l & 15) == 0) {
                    int o = OT * 16 + ((l >> 4) << 2) + r;
                    gout[(size_t)b * Cout + o] = m + bias[o];
                }
            }
        }
    }
}

// ---------------------------------------------------------------------------
// Head part 1: h1 = relu(g @ fw1^T + fb1). Grid 32*8.
// ---------------------------------------------------------------------------
__global__ __launch_bounds__(256) void head1_kernel(
    const float* __restrict__ g, const float* __restrict__ fw1,
    const float* __restrict__ fb1, float* __restrict__ h1out) {
    int bid = blockIdx.x;
    int b = bid >> 3, u = bid & 7;
    int o0 = u * 64;
    __shared__ float gs[1024];
    int t = threadIdx.x;
    for (int i = t; i < 1024; i += 256) gs[i] = g[(size_t)b * 1024 + i];
    __syncthreads();
    int o = o0 + (t >> 2), seg = t & 3;
    const float4* wr = (const float4*)&fw1[(size_t)o * 1024 + seg * 256];
    const float* gg0 = &gs[seg * 256];
    float acc = 0.f;
    for (int c = 0; c < 64; c++) {
        float4 wv = wr[c];
        const float* gg = &gg0[c * 4];
        acc += wv.x * gg[0] + wv.y * gg[1] + wv.z * gg[2] + wv.w * gg[3];
    }
    acc += __shfl_down(acc, 1);
    acc += __shfl_down(acc, 2);
    if (seg == 0) h1out[(size_t)b * 512 + o] = fmaxf(acc + fb1[o], 0.f);
}

// ---------------------------------------------------------------------------
// Head part 2: FC 512->256->40. One block per batch.
// ---------------------------------------------------------------------------
__global__ __launch_bounds__(256) void head2_kernel(
    const float* __restrict__ h1in,
    const float* __restrict__ fw2, const float* __restrict__ fb2,
    const float* __restrict__ fw3, const float* __restrict__ fb3,
    float* __restrict__ out) {
    int b = blockIdx.x;
    int t = threadIdx.x;
    __shared__ float h1[512];
    __shared__ float h2[256];
    for (int i = t; i < 512; i += 256) h1[i] = h1in[(size_t)b * 512 + i];
    __syncthreads();
    {
        float acc = fb2[t];
        const float4* wr = (const float4*)&fw2[(size_t)t * 512];
        for (int c = 0; c < 128; c++) {
            float4 wv = wr[c];
            acc += wv.x * h1[c * 4] + wv.y * h1[c * 4 + 1] + wv.z * h1[c * 4 + 2] + wv.w * h1[c * 4 + 3];
        }
        h2[t] = fmaxf(acc, 0.f);
    }
    __syncthreads();
    if (t < 40) {
        float acc = fb3[t];
        const float4* wr = (const float4*)&fw3[(size_t)t * 256];
        for (int c = 0; c < 64; c++) {
            float4 wv = wr[c];
            acc += wv.x * h2[c * 4] + wv.y * h2[c * 4 + 1] + wv.z * h2[c * 4 + 2] + wv.w * h2[c * 4 + 3];
        }
        out[b * 40 + t] = acc;
    }
}

extern "C" void kernel_launch(void* const* d_in, const int* in_sizes, int n_in,
                              void* d_out, int out_size, void* d_ws, size_t ws_size,
                              hipStream_t stream) {
    const float* x      = (const float*)d_in[0];
    const float* sa1_w1 = (const float*)d_in[1];
    const float* sa1_b1 = (const float*)d_in[2];
    const float* sa1_w2 = (const float*)d_in[3];
    const float* sa1_b2 = (const float*)d_in[4];
    const float* sa1_w3 = (const float*)d_in[5];
    const float* sa1_b3 = (const float*)d_in[6];
    const float* sa2_w1 = (const float*)d_in[7];
    const float* sa2_b1 = (const float*)d_in[8];
    const float* sa2_w2 = (const float*)d_in[9];
    const float* sa2_b2 = (const float*)d_in[10];
    const float* sa2_w3 = (const float*)d_in[11];
    const float* sa2_b3 = (const float*)d_in[12];
    const float* sa3_w1 = (const float*)d_in[13];
    const float* sa3_b1 = (const float*)d_in[14];
    const float* sa3_w2 = (const float*)d_in[15];
    const float* sa3_b2 = (const float*)d_in[16];
    const float* sa3_w3 = (const float*)d_in[17];
    const float* sa3_b3 = (const float*)d_in[18];
    const float* fc1_w  = (const float*)d_in[19];
    const float* fc1_b  = (const float*)d_in[20];
    const float* fc2_w  = (const float*)d_in[21];
    const float* fc2_b  = (const float*)d_in[22];
    const float* fc3_w  = (const float*)d_in[23];
    const float* fc3_b  = (const float*)d_in[24];

    char* ws = (char*)d_ws;
    const size_t MB = 1048576;
    const size_t KB = 1024;
    // Liveness map (intervals disjoint in space or time; 2-plane sizes):
    //   [0, 304KB)     s*w*f frags : wfrag#1 -> sa1/sa2_mfma
    //   [0.5, 2.5MB)   idx1 (int)  : knn#1 -> sa1_mfma
    //   [2.5, 3.0MB)   idx2 (u16)  : knn#2 -> sa2_mfma
    //   [3, 35MB)      a1t         : sa1_pre -> sa1_mfma
    //   [35, 43MB)     p1          : sa1_mfma -> sa2_pre
    //   [4, 12MB)      a2t         : sa2_pre -> sa2_mfma   (over dead a1t)
    //   [12, 16MB)     p2f (4MB)   : sa2_mfma -> sa3#1     (over dead a1t)
    //   [18, 22MB)     h1f (4MB)   : sa3#1 -> sa3#2        (over dead a1t)
    //   [24, 32MB)     h2f (8MB)   : sa3#2 -> sa3#3        (over dead a1t/p1)
    //   [36, 36.19MB)  g, h1hd     : sa3#3 -> head
    //   [36.5, 40MB)   w*f3 frags  : wfrag#2 (after sa2_pre; p1 dead) -> sa3
    unsigned short* s1w2f = (unsigned short*)(ws + 0);
    unsigned short* s1w3f = (unsigned short*)(ws + 32 * KB);
    unsigned short* s2w2f = (unsigned short*)(ws + 128 * KB);
    unsigned short* s2w3f = (unsigned short*)(ws + 224 * KB);
    int*            idx1  = (int*)(ws + 512 * KB);
    unsigned short* idx2  = (unsigned short*)(ws + 2560 * KB);  // 512 KB, u16
    float*          a1t   = (float*)(ws + 3 * MB);
    float*          p1    = (float*)(ws + 35 * MB);
    float*          a2t   = (float*)(ws + 4 * MB);
    unsigned short* p2f   = (unsigned short*)(ws + 12 * MB);
    unsigned short* h1f   = (unsigned short*)(ws + 18 * MB);
    unsigned short* h2f   = (unsigned short*)(ws + 24 * MB);
    float*          g     = (float*)(ws + 36 * MB);
    float*          h1hd  = (float*)(ws + 36 * MB + 128 * KB);
    unsigned short* w1f3  = (unsigned short*)(ws + 36 * MB + 512 * KB);
    unsigned short* w2f3  = (unsigned short*)(ws + 37 * MB);
    unsigned short* w3f3  = (unsigned short*)(ws + 38 * MB);

    // Early weight fragments (SA1+SA2), one launch.
    {
        WfragJobs jobs;
        jobs.j[0] = {sa1_w2, 64, 64, 0, 4, s1w2f};
        jobs.j[1] = {sa1_w3, 64, 64, 0, 8, s1w3f};
        jobs.j[2] = {sa2_w2, 128, 128, 0, 8, s2w2f};
        jobs.j[3] = {sa2_w3, 128, 128, 0, 16, s2w3f};
        jobs.start[0] = 0; jobs.start[1] = 8; jobs.start[2] = 24;
        jobs.start[3] = 56; jobs.start[4] = 120;
        wfrag_multi<<<120, 64, 0, stream>>>(jobs);
    }
    knn4r_kernel<16><<<32 * 128, 256, 0, stream>>>(x, 32, 512, idx1, nullptr);
    sa1_pre_kernel<<<32 * 32, 256, 0, stream>>>(x, sa1_w1, sa1_b1, a1t);
    sa1_mfma_kernel<<<32 * 256, 256, 0, stream>>>(x, a1t, idx1, sa1_w1,
                                                  s1w2f, sa1_b2, s1w3f, sa1_b3, p1);
    knn4r_kernel<2><<<32 * 32, 256, 0, stream>>>(x, 64, 128, nullptr, idx2);
    sa2_pre_kernel<<<32 * 4, 256, 0, stream>>>(x, p1, sa2_w1, sa2_b1, a2t);
    // SA3 weight fragments (p1/a1t dead after sa2_pre), one launch.
    {
        WfragJobs jobs;
        jobs.j[0] = {sa3_w1, 256, 259, 3, 16, w1f3};
        jobs.j[1] = {sa3_w2, 256, 256, 0, 32, w2f3};
        jobs.j[2] = {sa3_w3, 512, 512, 0, 64, w3f3};
        jobs.j[3] = {sa3_w3, 512, 512, 0, 64, w3f3};  // unused
        jobs.start[0] = 0; jobs.start[1] = 128; jobs.start[2] = 384;
        jobs.start[3] = 1408; jobs.start[4] = 1408;
        wfrag_multi<<<1408, 64, 0, stream>>>(jobs);
    }
    sa2_mfma_kernel<<<32 * 128, 256, 0, stream>>>(x, a2t, idx2, sa2_w1,
                                                  s2w2f, sa2_b2, s2w3f, sa2_b3, p2f);
    sa3_mfma_kernel<<<32 * 8, 64, 0, stream>>>(p2f, w1f3, sa3_b1, 8, 16, h1f, 8, nullptr, 0);
    sa3_mfma_kernel<<<32 * 16, 64, 0, stream>>>(h1f, w2f3, sa3_b2, 8, 32, h2f, 16, nullptr, 0);
    sa3_mfma_kernel<<<32 * 32, 64, 0, stream>>>(h2f, w3f3, sa3_b3, 16, 64, nullptr, 0, g, 1);
    head1_kernel<<<32 * 8, 256, 0, stream>>>(g, fc1_w, fc1_b, h1hd);
    head2_kernel<<<32, 256, 0, stream>>>(h1hd, fc2_w, fc2_b, fc3_w, fc3_b,
                                         (float*)d_out);
}

// Round 18
// 396.726 us; speedup vs baseline: 1.2624x; 1.2624x over previous
//
#include <hip/hip_runtime.h>
#include <hip/hip_bf16.h>

#define FLT_BIG 3.0e38f

typedef __attribute__((ext_vector_type(8))) short s8v;
typedef __attribute__((ext_vector_type(4))) float f4v;

// ---------------------------------------------------------------------------
// bf16 2-plane split, RNE. x ~= x0 + x1 with residual <= 2^-18 |x|.
// ---------------------------------------------------------------------------
__device__ inline void split2(float v, unsigned short& h0, unsigned short& h1) {
    unsigned int u = __float_as_uint(v);
    unsigned int r0 = (u + 0x7FFFu + ((u >> 16) & 1u)) >> 16;
    h0 = (unsigned short)r0;
    float r = v - __uint_as_float(r0 << 16);
    unsigned int u2 = __float_as_uint(r);
    h1 = (unsigned short)((u2 + 0x7FFFu + ((u2 >> 16) & 1u)) >> 16);
}

// MFMA plane-combo steps (2-plane): (1,0), (0,1), (0,0) — smallest first.
#define SA2_P1(AI, BI)                                                          \
    _Pragma("unroll") for (int oi = 0; oi < 2; oi++) {                          \
        _Pragma("unroll") for (int jf = 0; jf < 4; jf++)                        \
            acc1[oi][jf] = __builtin_amdgcn_mfma_f32_16x16x32_bf16(             \
                aw[oi][AI], bfr[jf][BI], acc1[oi][jf], 0, 0, 0);                \
    }
#define SA1_P1(AI, BI)                                                          \
    _Pragma("unroll") for (int jf = 0; jf < 4; jf++)                            \
        acc1[jf] = __builtin_amdgcn_mfma_f32_16x16x32_bf16(                     \
            aw[AI], bfr[jf][BI], acc1[jf], 0, 0, 0);
#define MM_P2(AI, BI)                                                           \
    _Pragma("unroll") for (int oi = 0; oi < 2; oi++) {                          \
        _Pragma("unroll") for (int jf = 0; jf < 4; jf++)                        \
            acc2[oi][jf] = __builtin_amdgcn_mfma_f32_16x16x32_bf16(             \
                af[jf][AI], gw[oi][BI], acc2[oi][jf], 0, 0, 0);                 \
    }
#define SA3_P(AI, BI)                                                           \
    _Pragma("unroll") for (int oi = 0; oi < 2; oi++) {                          \
        _Pragma("unroll") for (int j = 0; j < 4; j++)                           \
            acc[oi][ph * 4 + j] = __builtin_amdgcn_mfma_f32_16x16x32_bf16(      \
                aw[oi][AI], bfh[j][BI], acc[oi][ph * 4 + j], 0, 0, 0);          \
    }

// Monotonic key for d2, pinned FMA order (identical everywhere).
#define MKKEY(QX, QY, QZ, XS)                                                   \
    ({  float dot_ = fmaf((QZ), yz, fmaf((QY), yy, (QX) * yx));                 \
        float d2_ = fmaf(-2.0f, dot_, (XS) + ys);                               \
        unsigned int kk_ = __float_as_uint(d2_);                                \
        (kk_ & 0x80000000u) ? ~kk_ : (kk_ | 0x80000000u); })

// ---------------------------------------------------------------------------
// Multi-job weight fragment precompute (2 planes).
// ---------------------------------------------------------------------------
struct WfragJob { const float* W; int K, stride, off, no; unsigned short* out; };
struct WfragJobs { WfragJob j[4]; int start[5]; };

__global__ __launch_bounds__(64) void wfrag_multi(WfragJobs jobs) {
    int bid = blockIdx.x;
    int ji = 3;
    if (bid < jobs.start[1]) ji = 0;
    else if (bid < jobs.start[2]) ji = 1;
    else if (bid < jobs.start[3]) ji = 2;
    const WfragJob& J = jobs.j[ji];
    int lb = bid - jobs.start[ji];
    int l = threadIdx.x;
    int ks = lb / J.no, ot = lb - ks * J.no;
    int o = ot * 16 + (l & 15);
    int k0 = ks * 32 + (l >> 4) * 8;
    const float* src = J.W + (size_t)o * J.stride + J.off + k0;
    unsigned short h[2][8];
#pragma unroll
    for (int e = 0; e < 8; e++) split2(src[e], h[0][e], h[1][e]);
#pragma unroll
    for (int p = 0; p < 2; p++) {
        s8v v;
#pragma unroll
        for (int e = 0; e < 8; e++) v[e] = (short)h[p][e];
        *(s8v*)(J.out + ((size_t)(lb * 2 + p) * 64 + l) * 8) = v;
    }
}

// ---------------------------------------------------------------------------
// kNN: 4 queries per block, hist + classify passes. Optional u16 output
// (for P=128 whose indices are < 512).  [round-15 verified form]
// ---------------------------------------------------------------------------
#define KNN_CAP 192
__global__ __launch_bounds__(256) void knn4_kernel(
    const float* __restrict__ x, int N_pts, int K, int P,
    int* __restrict__ idx_out, unsigned short* __restrict__ idx16) {
    int bq = blockIdx.x;
    int pg = P >> 2;
    int b = bq / pg, p0 = (bq - b * pg) * 4;
    const float* xyz = x + (size_t)b * 24576;
    __shared__ unsigned int hist[2][2048];
    __shared__ unsigned int candK[4][KNN_CAP];
    __shared__ int candI[4][KNN_CAP];
    __shared__ int outIdx[4][64];
    __shared__ unsigned int cnts[4][2];
    __shared__ int sB[4], sM[4];
    __shared__ float qcoord[4][4];
    int t = threadIdx.x;
    int w = t >> 6, lane = t & 63;
    for (int i = t; i < 4096; i += 256) ((unsigned int*)hist)[i] = 0u;
    if (t < 8) cnts[t >> 1][t & 1] = 0u;
    float qx[4], qy[4], qz[4], xs[4];
#pragma unroll
    for (int q = 0; q < 4; q++) {
        float a = xyz[p0 + q], c1 = xyz[4096 + p0 + q], c2 = xyz[8192 + p0 + q];
        qx[q] = a; qy[q] = c1; qz[q] = c2;
        xs[q] = fmaf(c2, c2, fmaf(c1, c1, a * a));
    }
    if (t < 4) {
        qcoord[t][0] = qx[t]; qcoord[t][1] = qy[t];
        qcoord[t][2] = qz[t]; qcoord[t][3] = xs[t];
    }
    __syncthreads();
    for (int n = t; n < N_pts; n += 256) {
        float yx = xyz[n], yy = xyz[4096 + n], yz = xyz[8192 + n];
        float ys = fmaf(yz, yz, fmaf(yy, yy, yx * yx));
#pragma unroll
        for (int q = 0; q < 4; q++) {
            unsigned int key = MKKEY(qx[q], qy[q], qz[q], xs[q]);
            atomicAdd(&hist[q >> 1][key >> 21], 1u << ((q & 1) * 16));
        }
    }
    __syncthreads();
    {
        int pair = w >> 1, sh = (w & 1) * 16;
        unsigned int lsum = 0;
        for (int i = 0; i < 32; i++)
            lsum += (hist[pair][lane * 32 + i] >> sh) & 0xFFFFu;
        unsigned int incl = lsum;
        for (int ss = 1; ss < 64; ss <<= 1) {
            unsigned int v = (unsigned int)__shfl_up((int)incl, ss);
            if (lane >= ss) incl += v;
        }
        unsigned int excl = incl - lsum;
        if (excl < (unsigned)K && excl + lsum >= (unsigned)K) {
            unsigned int cum = excl;
            for (int i = 0; i < 32; i++) {
                unsigned int h = (hist[pair][lane * 32 + i] >> sh) & 0xFFFFu;
                if (cum < (unsigned)K && cum + h >= (unsigned)K) {
                    sB[w] = lane * 32 + i; sM[w] = (int)cum; break;
                }
                cum += h;
            }
        }
    }
    __syncthreads();
    for (int n = t; n < N_pts; n += 256) {
        float yx = xyz[n], yy = xyz[4096 + n], yz = xyz[8192 + n];
        float ys = fmaf(yz, yz, fmaf(yy, yy, yx * yx));
#pragma unroll
        for (int q = 0; q < 4; q++) {
            unsigned int key = MKKEY(qx[q], qy[q], qz[q], xs[q]);
            int bin = (int)(key >> 21);
            int Bq = sB[q];
            if (bin < Bq) {
                outIdx[q][atomicAdd(&cnts[q][0], 1u)] = n;
            } else if (bin == Bq) {
                unsigned int ci = atomicAdd(&cnts[q][1], 1u);
                if (ci < KNN_CAP) { candK[q][ci] = key; candI[q][ci] = n; }
            }
        }
    }
    __syncthreads();
    {
        int nc = (int)cnts[w][1];
        int m = sM[w], r = K - m, Bw = sB[w];
        if (nc <= KNN_CAP) {
            for (int ci = lane; ci < nc; ci += 64) {
                unsigned int ki = candK[w][ci];
                int ii = candI[w][ci];
                int rank = 0;
                for (int j = 0; j < nc; j++) {
                    unsigned int kj = candK[w][j];
                    rank += (kj < ki || (kj == ki && candI[w][j] < ii)) ? 1 : 0;
                }
                if (rank < r) outIdx[w][m + rank] = ii;
            }
        } else {
            float fqx = qcoord[w][0], fqy = qcoord[w][1];
            float fqz = qcoord[w][2], fxs = qcoord[w][3];
            unsigned int lastK = 0u; int lastI = -1;
            for (int rr = 0; rr < r; rr++) {
                unsigned int bk = 0xFFFFFFFFu; int bi = 0x7fffffff;
                for (int n = lane; n < N_pts; n += 64) {
                    float yx = xyz[n], yy = xyz[4096 + n], yz = xyz[8192 + n];
                    float ys = fmaf(yz, yz, fmaf(yy, yy, yx * yx));
                    unsigned int key = MKKEY(fqx, fqy, fqz, fxs);
                    if ((int)(key >> 21) == Bw) {
                        bool gt = (key > lastK) || (key == lastK && n > lastI);
                        if (gt && (key < bk || (key == bk && n < bi))) { bk = key; bi = n; }
                    }
                }
#pragma unroll
                for (int ss = 32; ss > 0; ss >>= 1) {
                    unsigned int ok = (unsigned int)__shfl_xor((int)bk, ss);
                    int oi = __shfl_xor(bi, ss);
                    if (ok < bk || (ok == bk && oi < bi)) { bk = ok; bi = oi; }
                }
                if (lane == 0) outIdx[w][m + rr] = bi;
                lastK = bk; lastI = bi;
            }
        }
    }
    __syncthreads();
    if (t < 4 * K) {
        int q = t / K, k = t - q * K;
        size_t off = ((size_t)(b * P) + p0 + q) * K + k;
        if (idx16) idx16[off] = (unsigned short)outIdx[q][k];
        else idx_out[off] = outIdx[q][k];
    }
}

// ---------------------------------------------------------------------------
// SA1 precompute: A1t[b][n][o] = b1[o] + sum_c w1[o][c]*x[b][c][n].
// ---------------------------------------------------------------------------
__global__ __launch_bounds__(256) void sa1_pre_kernel(
    const float* __restrict__ x, const float* __restrict__ w1, const float* __restrict__ b1,
    float* __restrict__ a1t) {
    int bid = blockIdx.x;
    int b = bid >> 5, nt = bid & 31, n0 = nt << 7;
    __shared__ float xsh[6 * 128];
    __shared__ float wt[6 * 68];
    const float* xb = x + (size_t)b * 24576;
    int t = threadIdx.x;
    for (int id = t; id < 768; id += 256) {
        int c = id >> 7, n = id & 127;
        xsh[c * 128 + n] = xb[c * 4096 + n0 + n];
    }
    for (int id = t; id < 384; id += 256) {
        int c = id >> 6, o = id & 63;
        wt[c * 68 + o] = w1[o * 6 + c];
    }
    __syncthreads();
    int o = t & 63, ng = t >> 6;
    float acc[32];
    float bias = b1[o];
#pragma unroll
    for (int j = 0; j < 32; j++) acc[j] = bias;
    for (int c = 0; c < 6; c++) {
        float w = wt[c * 68 + o];
        const float* f = &xsh[c * 128 + ng * 32];
#pragma unroll
        for (int j = 0; j < 32; j++) acc[j] += w * f[j];
    }
#pragma unroll
    for (int j = 0; j < 32; j++)
        a1t[((size_t)b * 4096 + n0 + ng * 32 + j) * 64 + o] = acc[j];
}

// ---------------------------------------------------------------------------
// SA1 MFMA fused (2-plane). Block = 2 queries, 256 thr.
// ---------------------------------------------------------------------------
__global__ __launch_bounds__(256) void sa1_mfma_kernel(
    const float* __restrict__ x, const float* __restrict__ a1t,
    const int* __restrict__ idx1, const float* __restrict__ w1,
    const unsigned short* __restrict__ w2f, const float* __restrict__ b2,
    const unsigned short* __restrict__ w3f, const float* __restrict__ b3,
    float* __restrict__ p1) {
    int bp = blockIdx.x;  // 32*256
    int b = bp >> 8, pp = bp & 255, p0 = pp * 2;
    __shared__ float dshq[2][64];
    __shared__ int nbr[64];
    __shared__ unsigned short A1buf[8 * 2 * 64 * 8];  // 16KB
    __shared__ float MX[2][128];
    const float* xb = x + (size_t)b * 24576;
    int t = threadIdx.x;
    int w = t >> 6, l = t & 63;
    int n16 = l & 15, og = l >> 4;
    if (t < 64) nbr[t] = idx1[((size_t)b * 512 + p0) * 32 + t];
    if (t < 128) {
        int qi = t >> 6, c = t & 63;
        float qx = xb[p0 + qi], qy = xb[4096 + p0 + qi], qz = xb[8192 + p0 + qi];
        dshq[qi][c] = -(w1[c * 6 + 0] * qx + w1[c * 6 + 1] * qy + w1[c * 6 + 2] * qz);
    }
    __syncthreads();
    int q = w >> 1;
    f4v acc1[4];
#pragma unroll
    for (int jf = 0; jf < 4; jf++) acc1[jf] = (f4v){0.f, 0.f, 0.f, 0.f};
    const float* gsrc = a1t + ((size_t)b * 4096 + nbr[w * 16 + n16]) * 64 + og * 8;
    f4v nv0 = *(const f4v*)(gsrc);
    f4v nv1 = *(const f4v*)(gsrc + 4);
    s8v nw[2];
    {
        const s8v* wr = (const s8v*)w2f;
#pragma unroll
        for (int pl = 0; pl < 2; pl++) nw[pl] = wr[(w * 2 + pl) * 64 + l];
    }
    for (int ks = 0; ks < 2; ks++) {
        f4v v0 = nv0, v1 = nv1;
        s8v aw[2];
#pragma unroll
        for (int pl = 0; pl < 2; pl++) aw[pl] = nw[pl];
        if (ks < 1) {
            nv0 = *(const f4v*)(gsrc + 32);
            nv1 = *(const f4v*)(gsrc + 36);
            const s8v* wr = (const s8v*)w2f + (size_t)4 * 2 * 64;
#pragma unroll
            for (int pl = 0; pl < 2; pl++) nw[pl] = wr[(w * 2 + pl) * 64 + l];
        }
        unsigned short* BFD = A1buf + (ks & 1) * 4096;
        const float* d = &dshq[q][ks * 32 + og * 8];
        s8v sp0, sp1;
#pragma unroll
        for (int e = 0; e < 8; e++) {
            float hv = fmaxf(((e < 4) ? v0[e] : v1[e - 4]) + d[e], 0.f);
            unsigned short h0, h1;
            split2(hv, h0, h1);
            sp0[e] = (short)h0; sp1[e] = (short)h1;
        }
        *(s8v*)&BFD[((w * 2 + 0) * 64 + l) * 8] = sp0;
        *(s8v*)&BFD[((w * 2 + 1) * 64 + l) * 8] = sp1;
        __syncthreads();
        s8v bfr[4][2];
#pragma unroll
        for (int jf = 0; jf < 4; jf++)
#pragma unroll
            for (int pl = 0; pl < 2; pl++)
                bfr[jf][pl] = *(const s8v*)&BFD[((jf * 2 + pl) * 64 + l) * 8];
        SA1_P1(1, 0) SA1_P1(0, 1) SA1_P1(0, 0)
    }
    __syncthreads();  // all waves done reading BF before handoff overwrites
    {
        f4v bv = *(const f4v*)(b2 + w * 16 + og * 4);
        int l2 = n16 + ((w & 1) * 2 + (og >> 1)) * 16;
        int half = og & 1;
#pragma unroll
        for (int jf = 0; jf < 4; jf++) {
            unsigned short hh[2][4];
#pragma unroll
            for (int r = 0; r < 4; r++) {
                float y = fmaxf(acc1[jf][r] + bv[r], 0.f);
                split2(y, hh[0][r], hh[1][r]);
            }
            int slot = (w >> 1) * 4 + jf;
#pragma unroll
            for (int pl = 0; pl < 2; pl++) {
                unsigned long long pk = (unsigned long long)hh[pl][0] |
                    ((unsigned long long)hh[pl][1] << 16) |
                    ((unsigned long long)hh[pl][2] << 32) |
                    ((unsigned long long)hh[pl][3] << 48);
                *(unsigned long long*)&A1buf[((slot * 2 + pl) * 64 + l2) * 8 + half * 4] = pk;
            }
        }
    }
    __syncthreads();
    f4v acc2[2][4];
#pragma unroll
    for (int oi = 0; oi < 2; oi++)
#pragma unroll
        for (int jf = 0; jf < 4; jf++) acc2[oi][jf] = (f4v){0.f, 0.f, 0.f, 0.f};
    for (int ks2 = 0; ks2 < 2; ks2++) {
        s8v af[4][2];
#pragma unroll
        for (int jf = 0; jf < 4; jf++)
#pragma unroll
            for (int pl = 0; pl < 2; pl++)
                af[jf][pl] = *(const s8v*)&A1buf[(((ks2 * 4 + jf) * 2 + pl) * 64 + l) * 8];
        const s8v* wr = (const s8v*)w3f + (size_t)(ks2 * 8) * 2 * 64;
        s8v gw[2][2];
#pragma unroll
        for (int oi = 0; oi < 2; oi++)
#pragma unroll
            for (int pl = 0; pl < 2; pl++)
                gw[oi][pl] = wr[((w * 2 + oi) * 2 + pl) * 64 + l];
        MM_P2(1, 0) MM_P2(0, 1) MM_P2(0, 0)
    }
#pragma unroll
    for (int oi = 0; oi < 2; oi++) {
        float m0 = fmaxf(fmaxf(acc2[oi][0][0], acc2[oi][0][1]),
                         fmaxf(acc2[oi][0][2], acc2[oi][0][3]));
        m0 = fmaxf(m0, fmaxf(fmaxf(acc2[oi][1][0], acc2[oi][1][1]),
                             fmaxf(acc2[oi][1][2], acc2[oi][1][3])));
        float m1 = fmaxf(fmaxf(acc2[oi][2][0], acc2[oi][2][1]),
                         fmaxf(acc2[oi][2][2], acc2[oi][2][3]));
        m1 = fmaxf(m1, fmaxf(fmaxf(acc2[oi][3][0], acc2[oi][3][1]),
                             fmaxf(acc2[oi][3][2], acc2[oi][3][3])));
        m0 = fmaxf(m0, __shfl_xor(m0, 16));
        m0 = fmaxf(m0, __shfl_xor(m0, 32));
        m1 = fmaxf(m1, __shfl_xor(m1, 16));
        m1 = fmaxf(m1, __shfl_xor(m1, 32));
        if (og == 0) {
            MX[0][(w * 2 + oi) * 16 + n16] = m0;
            MX[1][(w * 2 + oi) * 16 + n16] = m1;
        }
    }
    __syncthreads();
    {
        int o = t & 127, qq = t >> 7;
        p1[((size_t)b * 128 + o) * 512 + p0 + qq] = MX[qq][o] + b3[o];
    }
}

// ---------------------------------------------------------------------------
// SA2 precompute (fp32 exact).
// ---------------------------------------------------------------------------
__global__ __launch_bounds__(256) void sa2_pre_kernel(
    const float* __restrict__ x, const float* __restrict__ p1,
    const float* __restrict__ w1, const float* __restrict__ b1,
    float* __restrict__ a2t) {
    int bid = blockIdx.x;
    int b = bid >> 2, nt = bid & 3, n0 = nt << 7;
    __shared__ float ins[2][16 * 128];
    __shared__ float wt[2][16 * 132];
    const float* xb = x + (size_t)b * 24576;
    const float* p1b = p1 + (size_t)b * 65536;
    int t = threadIdx.x;
    int og = t >> 3, pg = t & 7;
    int o0 = og * 4;
    float acc[4][16];
    {
        float bl[4] = {b1[o0], b1[o0 + 1], b1[o0 + 2], b1[o0 + 3]};
#pragma unroll
        for (int oi = 0; oi < 4; oi++)
#pragma unroll
            for (int j = 0; j < 16; j++) acc[oi][j] = bl[oi];
    }
    for (int id = t; id < 16 * 128; id += 256) {
        int n = id & 127, c = id >> 7;
        ins[0][c * 128 + n] = (c < 3) ? xb[c * 4096 + n0 + n]
                                      : p1b[(size_t)(c - 3) * 512 + n0 + n];
    }
    for (int id = t; id < 2048; id += 256) {
        int c = id & 15, oo = id >> 4;
        wt[0][c * 132 + oo] = w1[oo * 131 + c];
    }
    __syncthreads();
    for (int ch = 0; ch < 9; ch++) {
        int cs = (ch == 8) ? 3 : 16;
        if (ch < 8) {
            int c0n = (ch + 1) * 16;
            int csn = (ch == 7) ? 3 : 16;
            int nb = (ch + 1) & 1;
            for (int id = t; id < csn * 128; id += 256) {
                int n = id & 127, c = id >> 7;
                int cg = c0n + c;
                ins[nb][c * 128 + n] = (cg < 3) ? xb[cg * 4096 + n0 + n]
                                                : p1b[(size_t)(cg - 3) * 512 + n0 + n];
            }
            for (int id = t; id < 2048; id += 256) {
                int c = id & 15, oo = id >> 4;
                if (c < csn) wt[nb][c * 132 + oo] = w1[oo * 131 + c0n + c];
            }
        }
        const float* wb = wt[ch & 1];
        const float* ib = ins[ch & 1];
        for (int cc = 0; cc < cs; cc++) {
            float4 wv = *(const float4*)&wb[cc * 132 + o0];
            float wl[4] = {wv.x, wv.y, wv.z, wv.w};
#pragma unroll
            for (int c4 = 0; c4 < 4; c4++) {
                float4 fv = *(const float4*)&ib[cc * 128 + pg * 4 + c4 * 32];
                float fl[4] = {fv.x, fv.y, fv.z, fv.w};
#pragma unroll
                for (int j = 0; j < 4; j++)
#pragma unroll
                    for (int oi = 0; oi < 4; oi++) acc[oi][c4 * 4 + j] += wl[oi] * fl[j];
            }
        }
        __syncthreads();
    }
#pragma unroll
    for (int c4 = 0; c4 < 4; c4++)
#pragma unroll
        for (int j = 0; j < 4; j++) {
            int n = n0 + pg * 4 + c4 * 32 + j;
            float4 v;
            v.x = acc[0][c4 * 4 + j]; v.y = acc[1][c4 * 4 + j];
            v.z = acc[2][c4 * 4 + j]; v.w = acc[3][c4 * 4 + j];
            *(float4*)&a2t[((size_t)b * 512 + n) * 128 + o0] = v;
        }
}

// ---------------------------------------------------------------------------
// SA2 MFMA fused (2-plane). idx2 is u16.
// ---------------------------------------------------------------------------
__global__ __launch_bounds__(256) void sa2_mfma_kernel(
    const float* __restrict__ x, const float* __restrict__ a2t,
    const unsigned short* __restrict__ idx2, const float* __restrict__ w1,
    const unsigned short* __restrict__ w2f, const float* __restrict__ b2,
    const unsigned short* __restrict__ w3f, const float* __restrict__ b3,
    unsigned short* __restrict__ p2f) {
    int bp = blockIdx.x;  // 32*128
    int b = bp >> 7, p = bp & 127;
    __shared__ float dsh[128];
    __shared__ int nbr[64];
    __shared__ unsigned short A2buf[16 * 2 * 64 * 8];  // 32KB
    __shared__ float MX[256];
    const float* xb = x + (size_t)b * 24576;
    int t = threadIdx.x;
    int w = t >> 6, l = t & 63;
    int n16 = l & 15, og = l >> 4;
    if (t < 64) nbr[t] = (int)idx2[((size_t)b * 128 + p) * 64 + t];
    if (t < 128) {
        float qx = xb[p], qy = xb[4096 + p], qz = xb[8192 + p];
        dsh[t] = -(w1[t * 131 + 0] * qx + w1[t * 131 + 1] * qy + w1[t * 131 + 2] * qz);
    }
    __syncthreads();
    f4v acc1[2][4];
#pragma unroll
    for (int oi = 0; oi < 2; oi++)
#pragma unroll
        for (int jf = 0; jf < 4; jf++) acc1[oi][jf] = (f4v){0.f, 0.f, 0.f, 0.f};
    const float* gsrc = a2t + ((size_t)b * 512 + nbr[w * 16 + n16]) * 128 + og * 8;
    f4v nv0 = *(const f4v*)(gsrc);
    f4v nv1 = *(const f4v*)(gsrc + 4);
    s8v nw[2][2];
    {
        const s8v* wr = (const s8v*)w2f;
#pragma unroll
        for (int oi = 0; oi < 2; oi++)
#pragma unroll
            for (int pl = 0; pl < 2; pl++)
                nw[oi][pl] = wr[((w * 2 + oi) * 2 + pl) * 64 + l];
    }
    for (int ks = 0; ks < 4; ks++) {
        f4v v0 = nv0, v1 = nv1;
        s8v aw[2][2];
#pragma unroll
        for (int oi = 0; oi < 2; oi++)
#pragma unroll
            for (int pl = 0; pl < 2; pl++) aw[oi][pl] = nw[oi][pl];
        if (ks < 3) {
            nv0 = *(const f4v*)(gsrc + (ks + 1) * 32);
            nv1 = *(const f4v*)(gsrc + (ks + 1) * 32 + 4);
            const s8v* wr = (const s8v*)w2f + (size_t)((ks + 1) * 8) * 2 * 64;
#pragma unroll
            for (int oi = 0; oi < 2; oi++)
#pragma unroll
                for (int pl = 0; pl < 2; pl++)
                    nw[oi][pl] = wr[((w * 2 + oi) * 2 + pl) * 64 + l];
        }
        unsigned short* BFD = A2buf + (ks & 1) * 4096;
        const float* d = &dsh[ks * 32 + og * 8];
        s8v sp0, sp1;
#pragma unroll
        for (int e = 0; e < 8; e++) {
            float hv = fmaxf(((e < 4) ? v0[e] : v1[e - 4]) + d[e], 0.f);
            unsigned short h0, h1;
            split2(hv, h0, h1);
            sp0[e] = (short)h0; sp1[e] = (short)h1;
        }
        *(s8v*)&BFD[((w * 2 + 0) * 64 + l) * 8] = sp0;
        *(s8v*)&BFD[((w * 2 + 1) * 64 + l) * 8] = sp1;
        __syncthreads();
        s8v bfr[4][2];
#pragma unroll
        for (int jf = 0; jf < 4; jf++)
#pragma unroll
            for (int pl = 0; pl < 2; pl++)
                bfr[jf][pl] = *(const s8v*)&BFD[((jf * 2 + pl) * 64 + l) * 8];
        SA2_P1(1, 0) SA2_P1(0, 1) SA2_P1(0, 0)
    }
    __syncthreads();  // all waves done reading BF before handoff overwrites
#pragma unroll
    for (int oi = 0; oi < 2; oi++) {
        int ot = w * 2 + oi;
        f4v bv = *(const f4v*)(b2 + ot * 16 + og * 4);
        int l2 = n16 + (oi * 2 + (og >> 1)) * 16;
        int half = og & 1;
#pragma unroll
        for (int jf = 0; jf < 4; jf++) {
            unsigned short hh[2][4];
#pragma unroll
            for (int r = 0; r < 4; r++) {
                float y = fmaxf(acc1[oi][jf][r] + bv[r], 0.f);
                split2(y, hh[0][r], hh[1][r]);
            }
            int slot = w * 4 + jf;
#pragma unroll
            for (int pl = 0; pl < 2; pl++) {
                unsigned long long pk = (unsigned long long)hh[pl][0] |
                    ((unsigned long long)hh[pl][1] << 16) |
                    ((unsigned long long)hh[pl][2] << 32) |
                    ((unsigned long long)hh[pl][3] << 48);
                *(unsigned long long*)&A2buf[((slot * 2 + pl) * 64 + l2) * 8 + half * 4] = pk;
            }
        }
    }
    __syncthreads();
#pragma unroll
    for (int half2 = 0; half2 < 2; half2++) {
        f4v acc2[2][4];
#pragma unroll
        for (int oi = 0; oi < 2; oi++)
#pragma unroll
            for (int jf = 0; jf < 4; jf++) acc2[oi][jf] = (f4v){0.f, 0.f, 0.f, 0.f};
        for (int ks2 = 0; ks2 < 4; ks2++) {
            s8v af[4][2];
#pragma unroll
            for (int jf = 0; jf < 4; jf++)
#pragma unroll
                for (int pl = 0; pl < 2; pl++)
                    af[jf][pl] = *(const s8v*)&A2buf[(((ks2 * 4 + jf) * 2 + pl) * 64 + l) * 8];
            const s8v* wr = (const s8v*)w3f + (size_t)(ks2 * 16) * 2 * 64;
            s8v gw[2][2];
#pragma unroll
            for (int oi = 0; oi < 2; oi++)
#pragma unroll
                for (int pl = 0; pl < 2; pl++)
                    gw[oi][pl] = wr[((w * 4 + half2 * 2 + oi) * 2 + pl) * 64 + l];
            MM_P2(1, 0) MM_P2(0, 1) MM_P2(0, 0)
        }
#pragma unroll
        for (int oi = 0; oi < 2; oi++) {
            float m = -FLT_BIG;
#pragma unroll
            for (int jf = 0; jf < 4; jf++) {
                float mj = fmaxf(fmaxf(acc2[oi][jf][0], acc2[oi][jf][1]),
                                 fmaxf(acc2[oi][jf][2], acc2[oi][jf][3]));
                m = fmaxf(m, mj);
            }
            m = fmaxf(m, __shfl_xor(m, 16));
            m = fmaxf(m, __shfl_xor(m, 32));
            if (og == 0) MX[(w * 4 + half2 * 2 + oi) * 16 + n16] = m;
        }
    }
    __syncthreads();
    {   // write p2 channel t for point p as SA3-layer1 B-frag planes (2-plane)
        float val = MX[t] + b3[t];
        unsigned short h0, h1;
        split2(val, h0, h1);
        int pt = p >> 4;
        int ks = t >> 5, kl = t & 31;
        int l2 = (p & 15) + (kl >> 3) * 16;
        int e = kl & 7;
        size_t fb = (((size_t)b * 64 + ks * 8 + pt) * 2) * 512 + l2 * 8 + e;
        p2f[fb] = h0;
        p2f[fb + 512] = h1;
    }
}

// ---------------------------------------------------------------------------
// SA3 GEMM over 128 points, MFMA, 2-plane frag I/O.
// ---------------------------------------------------------------------------
__global__ __launch_bounds__(64) void sa3_mfma_kernel(
    const unsigned short* __restrict__ hf_in, const unsigned short* __restrict__ wf,
    const float* __restrict__ bias, int nks, int noCout,
    unsigned short* __restrict__ hf_out, int nksOut,
    float* __restrict__ gout, int reduce) {
    int nb = noCout >> 1;
    int bid = blockIdx.x;
    int b = bid / nb, u = bid - b * nb;
    int ot0 = u * 2;
    int l = threadIdx.x;
    f4v acc[2][8];
#pragma unroll
    for (int oi = 0; oi < 2; oi++)
#pragma unroll
        for (int j = 0; j < 8; j++) acc[oi][j] = (f4v){0.f, 0.f, 0.f, 0.f};
    const unsigned short* hb = hf_in + (size_t)b * nks * 8 * 2 * 512;
    for (int ks = 0; ks < nks; ks++) {
        s8v aw[2][2];
#pragma unroll
        for (int oi = 0; oi < 2; oi++)
#pragma unroll
            for (int pl = 0; pl < 2; pl++)
                aw[oi][pl] = *(const s8v*)&wf[(((size_t)(ks * noCout + ot0 + oi)) * 2 + pl) * 512 + l * 8];
#pragma unroll
        for (int ph = 0; ph < 2; ph++) {
            s8v bfh[4][2];
#pragma unroll
            for (int j = 0; j < 4; j++)
#pragma unroll
                for (int pl = 0; pl < 2; pl++)
                    bfh[j][pl] = *(const s8v*)&hb[(((size_t)(ks * 8 + ph * 4 + j)) * 2 + pl) * 512 + l * 8];
            SA3_P(1, 0) SA3_P(0, 1) SA3_P(0, 0)
        }
    }
    if (!reduce) {
#pragma unroll
        for (int oi = 0; oi < 2; oi++) {
            int OT = ot0 + oi;
            f4v bv = *(const f4v*)(bias + OT * 16 + (l >> 4) * 4);
            int ksp = OT >> 1;
            int l2 = (l & 15) + ((OT & 1) * 2 + ((l >> 4) >> 1)) * 16;
            int base4 = ((l >> 4) & 1) * 4;
#pragma unroll
            for (int pt = 0; pt < 8; pt++) {
                unsigned short hh[2][4];
#pragma unroll
                for (int r = 0; r < 4; r++) {
                    float y = fmaxf(acc[oi][pt][r] + bv[r], 0.f);
                    split2(y, hh[0][r], hh[1][r]);
                }
#pragma unroll
                for (int pl = 0; pl < 2; pl++) {
                    unsigned long long pk = (unsigned long long)hh[pl][0] |
                        ((unsigned long long)hh[pl][1] << 16) |
                        ((unsigned long long)hh[pl][2] << 32) |
                        ((unsigned long long)hh[pl][3] << 48);
                    *(unsigned long long*)&hf_out[
                        (((size_t)b * nksOut * 8 + ksp * 8 + pt) * 2 + pl) * 512 + l2 * 8 + base4] = pk;
                }
            }
        }
    } else {
        int Cout = noCout * 16;
#pragma unroll
        for (int oi = 0; oi < 2; oi++) {
            int OT = ot0 + oi;
#pragma unroll
            for (int r = 0; r < 4; r++) {
                float m = acc[oi][0][r];
#pragma unroll
                for (int pt = 1; pt < 8; pt++) m = fmaxf(m, acc[oi][pt][r]);
                m = fmaxf(m, __shfl_xor(m, 1));
                m = fmaxf(m, __shfl_xor(m, 2));
                m = fmaxf(m, __shfl_xor(m, 4));
                m = fmaxf(m, __shfl_xor(m, 8));
                if ((l & 15) == 0) {
                    int o = OT * 16 + ((l >> 4) << 2) + r;
                    gout[(size_t)b * Cout + o] = m + bias[o];
                }
            }
        }
    }
}

// ---------------------------------------------------------------------------
// Head part 1: h1 = relu(g @ fw1^T + fb1). Grid 32*8.
// ---------------------------------------------------------------------------
__global__ __launch_bounds__(256) void head1_kernel(
    const float* __restrict__ g, const float* __restrict__ fw1,
    const float* __restrict__ fb1, float* __restrict__ h1out) {
    int bid = blockIdx.x;
    int b = bid >> 3, u = bid & 7;
    int o0 = u * 64;
    __shared__ float gs[1024];
    int t = threadIdx.x;
    for (int i = t; i < 1024; i += 256) gs[i] = g[(size_t)b * 1024 + i];
    __syncthreads();
    int o = o0 + (t >> 2), seg = t & 3;
    const float4* wr = (const float4*)&fw1[(size_t)o * 1024 + seg * 256];
    const float* gg0 = &gs[seg * 256];
    float acc = 0.f;
    for (int c = 0; c < 64; c++) {
        float4 wv = wr[c];
        const float* gg = &gg0[c * 4];
        acc += wv.x * gg[0] + wv.y * gg[1] + wv.z * gg[2] + wv.w * gg[3];
    }
    acc += __shfl_down(acc, 1);
    acc += __shfl_down(acc, 2);
    if (seg == 0) h1out[(size_t)b * 512 + o] = fmaxf(acc + fb1[o], 0.f);
}

// ---------------------------------------------------------------------------
// Head part 2: FC 512->256->40. One block per batch.
// ---------------------------------------------------------------------------
__global__ __launch_bounds__(256) void head2_kernel(
    const float* __restrict__ h1in,
    const float* __restrict__ fw2, const float* __restrict__ fb2,
    const float* __restrict__ fw3, const float* __restrict__ fb3,
    float* __restrict__ out) {
    int b = blockIdx.x;
    int t = threadIdx.x;
    __shared__ float h1[512];
    __shared__ float h2[256];
    for (int i = t; i < 512; i += 256) h1[i] = h1in[(size_t)b * 512 + i];
    __syncthreads();
    {
        float acc = fb2[t];
        const float4* wr = (const float4*)&fw2[(size_t)t * 512];
        for (int c = 0; c < 128; c++) {
            float4 wv = wr[c];
            acc += wv.x * h1[c * 4] + wv.y * h1[c * 4 + 1] + wv.z * h1[c * 4 + 2] + wv.w * h1[c * 4 + 3];
        }
        h2[t] = fmaxf(acc, 0.f);
    }
    __syncthreads();
    if (t < 40) {
        float acc = fb3[t];
        const float4* wr = (const float4*)&fw3[(size_t)t * 256];
        for (int c = 0; c < 64; c++) {
            float4 wv = wr[c];
            acc += wv.x * h2[c * 4] + wv.y * h2[c * 4 + 1] + wv.z * h2[c * 4 + 2] + wv.w * h2[c * 4 + 3];
        }
        out[b * 40 + t] = acc;
    }
}

extern "C" void kernel_launch(void* const* d_in, const int* in_sizes, int n_in,
                              void* d_out, int out_size, void* d_ws, size_t ws_size,
                              hipStream_t stream) {
    const float* x      = (const float*)d_in[0];
    const float* sa1_w1 = (const float*)d_in[1];
    const float* sa1_b1 = (const float*)d_in[2];
    const float* sa1_w2 = (const float*)d_in[3];
    const float* sa1_b2 = (const float*)d_in[4];
    const float* sa1_w3 = (const float*)d_in[5];
    const float* sa1_b3 = (const float*)d_in[6];
    const float* sa2_w1 = (const float*)d_in[7];
    const float* sa2_b1 = (const float*)d_in[8];
    const float* sa2_w2 = (const float*)d_in[9];
    const float* sa2_b2 = (const float*)d_in[10];
    const float* sa2_w3 = (const float*)d_in[11];
    const float* sa2_b3 = (const float*)d_in[12];
    const float* sa3_w1 = (const float*)d_in[13];
    const float* sa3_b1 = (const float*)d_in[14];
    const float* sa3_w2 = (const float*)d_in[15];
    const float* sa3_b2 = (const float*)d_in[16];
    const float* sa3_w3 = (const float*)d_in[17];
    const float* sa3_b3 = (const float*)d_in[18];
    const float* fc1_w  = (const float*)d_in[19];
    const float* fc1_b  = (const float*)d_in[20];
    const float* fc2_w  = (const float*)d_in[21];
    const float* fc2_b  = (const float*)d_in[22];
    const float* fc3_w  = (const float*)d_in[23];
    const float* fc3_b  = (const float*)d_in[24];

    char* ws = (char*)d_ws;
    const size_t MB = 1048576;
    const size_t KB = 1024;
    // Liveness map (intervals disjoint in space or time; 2-plane sizes):
    //   [0, 304KB)     s*w*f frags : wfrag#1 -> sa1/sa2_mfma
    //   [0.5, 2.5MB)   idx1 (int)  : knn#1 -> sa1_mfma
    //   [2.5, 3.0MB)   idx2 (u16)  : knn#2 -> sa2_mfma
    //   [3, 35MB)      a1t         : sa1_pre -> sa1_mfma
    //   [35, 43MB)     p1          : sa1_mfma -> sa2_pre
    //   [4, 12MB)      a2t         : sa2_pre -> sa2_mfma   (over dead a1t)
    //   [12, 16MB)     p2f (4MB)   : sa2_mfma -> sa3#1     (over dead a1t)
    //   [18, 22MB)     h1f (4MB)   : sa3#1 -> sa3#2        (over dead a1t)
    //   [24, 32MB)     h2f (8MB)   : sa3#2 -> sa3#3        (over dead a1t/p1)
    //   [36, 36.19MB)  g, h1hd     : sa3#3 -> head
    //   [36.5, 40MB)   w*f3 frags  : wfrag#2 (after sa2_pre; p1 dead) -> sa3
    unsigned short* s1w2f = (unsigned short*)(ws + 0);
    unsigned short* s1w3f = (unsigned short*)(ws + 32 * KB);
    unsigned short* s2w2f = (unsigned short*)(ws + 128 * KB);
    unsigned short* s2w3f = (unsigned short*)(ws + 224 * KB);
    int*            idx1  = (int*)(ws + 512 * KB);
    unsigned short* idx2  = (unsigned short*)(ws + 2560 * KB);  // 512 KB, u16
    float*          a1t   = (float*)(ws + 3 * MB);
    float*          p1    = (float*)(ws + 35 * MB);
    float*          a2t   = (float*)(ws + 4 * MB);
    unsigned short* p2f   = (unsigned short*)(ws + 12 * MB);
    unsigned short* h1f   = (unsigned short*)(ws + 18 * MB);
    unsigned short* h2f   = (unsigned short*)(ws + 24 * MB);
    float*          g     = (float*)(ws + 36 * MB);
    float*          h1hd  = (float*)(ws + 36 * MB + 128 * KB);
    unsigned short* w1f3  = (unsigned short*)(ws + 36 * MB + 512 * KB);
    unsigned short* w2f3  = (unsigned short*)(ws + 37 * MB);
    unsigned short* w3f3  = (unsigned short*)(ws + 38 * MB);

    // Early weight fragments (SA1+SA2), one launch.
    {
        WfragJobs jobs;
        jobs.j[0] = {sa1_w2, 64, 64, 0, 4, s1w2f};
        jobs.j[1] = {sa1_w3, 64, 64, 0, 8, s1w3f};
        jobs.j[2] = {sa2_w2, 128, 128, 0, 8, s2w2f};
        jobs.j[3] = {sa2_w3, 128, 128, 0, 16, s2w3f};
        jobs.start[0] = 0; jobs.start[1] = 8; jobs.start[2] = 24;
        jobs.start[3] = 56; jobs.start[4] = 120;
        wfrag_multi<<<120, 64, 0, stream>>>(jobs);
    }
    knn4_kernel<<<32 * 128, 256, 0, stream>>>(x, 4096, 32, 512, idx1, nullptr);
    sa1_pre_kernel<<<32 * 32, 256, 0, stream>>>(x, sa1_w1, sa1_b1, a1t);
    sa1_mfma_kernel<<<32 * 256, 256, 0, stream>>>(x, a1t, idx1, sa1_w1,
                                                  s1w2f, sa1_b2, s1w3f, sa1_b3, p1);
    knn4_kernel<<<32 * 32, 256, 0, stream>>>(x, 512, 64, 128, nullptr, idx2);
    sa2_pre_kernel<<<32 * 4, 256, 0, stream>>>(x, p1, sa2_w1, sa2_b1, a2t);
    // SA3 weight fragments (p1/a1t dead after sa2_pre), one launch.
    {
        WfragJobs jobs;
        jobs.j[0] = {sa3_w1, 256, 259, 3, 16, w1f3};
        jobs.j[1] = {sa3_w2, 256, 256, 0, 32, w2f3};
        jobs.j[2] = {sa3_w3, 512, 512, 0, 64, w3f3};
        jobs.j[3] = {sa3_w3, 512, 512, 0, 64, w3f3};  // unused
        jobs.start[0] = 0; jobs.start[1] = 128; jobs.start[2] = 384;
        jobs.start[3] = 1408; jobs.start[4] = 1408;
        wfrag_multi<<<1408, 64, 0, stream>>>(jobs);
    }
    sa2_mfma_kernel<<<32 * 128, 256, 0, stream>>>(x, a2t, idx2, sa2_w1,
                                                  s2w2f, sa2_b2, s2w3f, sa2_b3, p2f);
    sa3_mfma_kernel<<<32 * 8, 64, 0, stream>>>(p2f, w1f3, sa3_b1, 8, 16, h1f, 8, nullptr, 0);
    sa3_mfma_kernel<<<32 * 16, 64, 0, stream>>>(h1f, w2f3, sa3_b2, 8, 32, h2f, 16, nullptr, 0);
    sa3_mfma_kernel<<<32 * 32, 64, 0, stream>>>(h2f, w3f3, sa3_b3, 16, 64, nullptr, 0, g, 1);
    head1_kernel<<<32 * 8, 256, 0, stream>>>(g, fc1_w, fc1_b, h1hd);
    head2_kernel<<<32, 256, 0, stream>>>(h1hd, fc2_w, fc2_b, fc3_w, fc3_b,
                                         (float*)d_out);
}